// Round 13
// baseline (212.136 us; speedup 1.0000x reference)
//
#include <hip/hip_runtime.h>
#include <stdint.h>

typedef unsigned short u16;
typedef unsigned int u32;

#define B_    2
#define DK    64
#define T_    2048
#define S_    2048
#define CI    512
#define CO    512
#define E_    512

typedef short  short8 __attribute__((ext_vector_type(8)));
typedef __bf16 bf16x8 __attribute__((ext_vector_type(8)));
typedef float  f32x4  __attribute__((ext_vector_type(4)));

static __device__ __forceinline__ u16 f2bf(float f) {
    return __builtin_bit_cast(u16, (__bf16)f);
}

static __device__ __forceinline__ float bf2f(u16 h) {
    return __uint_as_float((u32)h << 16);
}

static __device__ __forceinline__ short8 ld8(const u16* p) {
    return *(const short8*)p;
}

static __device__ __forceinline__ f32x4 mfma_bf16(short8 a, short8 b, f32x4 c) {
    return __builtin_amdgcn_mfma_f32_16x16x32_bf16(
        __builtin_bit_cast(bf16x8, a), __builtin_bit_cast(bf16x8, b), c, 0, 0, 0);
}

// ---------------- fused prep: x/y transpose + weight cvt + mask^T (+nonzero detect) ----------------
__global__ __launch_bounds__(256) void k_prep(const float* __restrict__ x, const float* __restrict__ y,
                                              const float* __restrict__ wk, const float* __restrict__ wv,
                                              const float* __restrict__ wq, const float* __restrict__ wf,
                                              const float* __restrict__ mask,
                                              u16* __restrict__ xt, u16* __restrict__ yt,
                                              u16* __restrict__ wkb, u16* __restrict__ wvb,
                                              u16* __restrict__ wqb, u16* __restrict__ wfb,
                                              u16* __restrict__ mt, u32* __restrict__ mflag) {
    __shared__ float tile[32][33];
    int bid = blockIdx.x;
    if (bid < 4096) {
        // transpose + cvt: src[b][i][t] f32 -> dst[b][t][i] bf16
        int bx = bid & 63, by = (bid >> 6) & 15, bz = bid >> 10;
        int tsel = bz >> 1, b = bz & 1;
        const float* src = tsel ? y : x;
        u16* dst = tsel ? yt : xt;
        int t0 = bx * 32, i0 = by * 32;
        int tx = threadIdx.x & 31, ty = threadIdx.x >> 5;
#pragma unroll
        for (int r = 0; r < 4; r++)
            tile[ty + r * 8][tx] = src[(size_t)(b * CI + i0 + ty + r * 8) * T_ + t0 + tx];
        __syncthreads();
#pragma unroll
        for (int r = 0; r < 4; r++)
            dst[(size_t)(b * T_ + t0 + ty + r * 8) * CI + i0 + tx] = f2bf(tile[tx][ty + r * 8]);
    } else if (bid < 4608) {
        // weight cvt, 8 elems/thread (512 blocks x 256 thr x 8 = 1M elems)
        int off = ((bid - 4096) * 256 + threadIdx.x) * 8;
        int w = off >> 18, r = off & 262143;
        const float* s = (w == 0) ? wk : (w == 1) ? wv : (w == 2) ? wq : wf;
        u16* d = (w == 0) ? wkb : (w == 1) ? wvb : (w == 2) ? wqb : wfb;
        float4 a0 = *(const float4*)(s + r);
        float4 a1 = *(const float4*)(s + r + 4);
        short8 o;
        o[0] = f2bf(a0.x); o[1] = f2bf(a0.y); o[2] = f2bf(a0.z); o[3] = f2bf(a0.w);
        o[4] = f2bf(a1.x); o[5] = f2bf(a1.y); o[6] = f2bf(a1.z); o[7] = f2bf(a1.w);
        *(short8*)(d + r) = o;
    } else {
        // mask transpose + pre-scale: mask[t][s] f32 -> mt[s][t] bf16*msc; detect any-nonzero
        int mb = bid - 4608;
        int t0 = (mb & 63) * 32, s0 = (mb >> 6) * 32;
        int tx = threadIdx.x & 31, ty = threadIdx.x >> 5;
        const float msc = 0.125f * 1.44269504088896f;
        bool nz = false;
#pragma unroll
        for (int r = 0; r < 4; r++) {
            float v = mask[(size_t)(t0 + ty + r * 8) * S_ + s0 + tx];
            tile[ty + r * 8][tx] = v;
            nz |= (v != 0.0f);
        }
        if (mflag && __any(nz) && (threadIdx.x & 63) == 0)
            atomicOr(mflag, 1u);
        __syncthreads();
#pragma unroll
        for (int r = 0; r < 4; r++)
            mt[(size_t)(s0 + ty + r * 8) * T_ + t0 + tx] = f2bf(tile[tx][ty + r * 8] * msc);
    }
}

// ---------------- fused projection GEMMs (64x64 tiles, pipelined K-loop) ----------------
// R11 post-mortem: non-attn block (~143us) invariant & likely latency-bound at 3
// waves/SIMD. Retile: block 64t x 64e (4 waves, wave 32x32), 512 blocks/GEMM ->
// grid 1536 = 6 blocks/CU = 24 waves/CU. Half the register state, 2x the TLP.
// p = p_base + (blockIdx.x>>9): 0=Q (yt->QT, pre-scaled by sc), 1=K, 2=V.
__global__ __launch_bounds__(256) void k_proj3(const u16* __restrict__ xt, const u16* __restrict__ yt,
                                               const u16* __restrict__ wkb, const u16* __restrict__ wvb,
                                               const u16* __restrict__ wqb,
                                               u16* __restrict__ ktd, u16* __restrict__ vtd,
                                               u16* __restrict__ qtd, int p_base) {
    int bi = blockIdx.x;
    int p = p_base + (bi >> 9);
    int r = bi & 511;
    int et = r & 7, tt = r >> 3;          // et: 64-e tile (8), tt: 64-t tile (64, b folded)
    int wv = threadIdx.x >> 6, lane = threadIdx.x & 63;
    int col = lane & 15, q = lane >> 4;
    int b = tt >> 5;
    int t0 = (tt & 31) * 64 + (wv >> 1) * 32;
    int e0 = et * 64 + (wv & 1) * 32;
    const u16* src = (p == 0) ? yt : xt;
    const u16* wb  = (p == 0) ? wqb : (p == 1) ? wkb : wvb;
    const u16* ap0 = src + (size_t)(b * T_ + t0 + col) * CI + q * 8;
    const u16* bp0 = wb + (size_t)(e0 + col) * CI + q * 8;
    f32x4 acc[2][2] = {};
    short8 a0 = ld8(ap0), a1 = ld8(ap0 + 16 * CI);
    short8 b0 = ld8(bp0), b1 = ld8(bp0 + 16 * CI);
#pragma unroll
    for (int ks = 0; ks < 16; ks++) {
        short8 na0, na1, nb0, nb1;
        if (ks < 15) {
            na0 = ld8(ap0 + (ks + 1) * 32);
            na1 = ld8(ap0 + 16 * CI + (ks + 1) * 32);
            nb0 = ld8(bp0 + (ks + 1) * 32);
            nb1 = ld8(bp0 + 16 * CI + (ks + 1) * 32);
        }
        acc[0][0] = mfma_bf16(a0, b0, acc[0][0]); acc[1][0] = mfma_bf16(a1, b0, acc[1][0]);
        acc[0][1] = mfma_bf16(a0, b1, acc[0][1]); acc[1][1] = mfma_bf16(a1, b1, acc[1][1]);
        if (ks < 15) {
            a0 = na0; a1 = na1; b0 = nb0; b1 = nb1;
        }
    }
    // Q gets the softmax scale folded in (sc = 0.125 * log2(e)); K/V unscaled.
    float qs = (p == 0) ? 0.180336880f : 1.0f;
    u16* dst = (p == 0) ? qtd : (p == 1) ? ktd : vtd;
    if (p < 2) {
#pragma unroll
        for (int mt = 0; mt < 2; mt++)
#pragma unroll
            for (int nt = 0; nt < 2; nt++) {
                int e = e0 + nt * 16 + col, h = e >> 6, k = e & 63;
                u16* dp = dst + ((size_t)(b * 8 + h) * T_ + t0 + mt * 16 + q * 4) * DK + k;
                dp[0] = f2bf(acc[mt][nt][0] * qs);
                dp[DK] = f2bf(acc[mt][nt][1] * qs);
                dp[2 * DK] = f2bf(acc[mt][nt][2] * qs);
                dp[3 * DK] = f2bf(acc[mt][nt][3] * qs);
            }
    } else {
#pragma unroll
        for (int mt = 0; mt < 2; mt++)
#pragma unroll
            for (int nt = 0; nt < 2; nt++) {
                int e = e0 + nt * 16 + col, h = e >> 6, v = e & 63;
                uint2 pk;
                pk.x = f2bf(acc[mt][nt][0]) | ((u32)f2bf(acc[mt][nt][1]) << 16);
                pk.y = f2bf(acc[mt][nt][2]) | ((u32)f2bf(acc[mt][nt][3]) << 16);
                *(uint2*)(dst + ((size_t)(b * 8 + h) * DK + v) * T_ + t0 + mt * 16 + q * 4) = pk;
            }
    }
}

// ---------------- flash attention: runtime mask-skip, barrier-free inner loop ----------------
// R11 post-mortem: maskless V-ping-pong needs ~132 arch VGPRs but the allocator
// hard-pins 128 (HW granularity 64/128/256) -> 11MB scratch spill ate the gain.
// This version: maskless path = R8's proven register shape (V TOP-LOADED in-iter,
// K ping-pong only, ~105 arch without mask regs) -> zero spill + R11's FETCH win.
// Masked path unchanged (R8 structure + MT bf16 stream).

// masked iteration (mv pre-scaled, Q pre-scaled -> add)
#define ATTN_ITER_M(T0, KC, MC4, MCF, KN, MN4, MNF, TN)  do {                       \
    short8 vb0 = ld8(vbase + (T0));                                                 \
    short8 vb1 = ld8(vbase + 16 * (size_t)T_ + (T0));                               \
    short8 vb2 = ld8(vbase + 32 * (size_t)T_ + (T0));                               \
    short8 vb3 = ld8(vbase + 48 * (size_t)T_ + (T0));                               \
    f32x4 s0g[4], s1g[4];                                                           \
    __builtin_amdgcn_s_setprio(1);                                                  \
    _Pragma("unroll") for (int g = 0; g < 4; g++) {                                 \
        f32x4 z = {};                                                               \
        s0g[g] = mfma_bf16(KC[0], qa[g][0], z);                                     \
        s0g[g] = mfma_bf16(KC[1], qa[g][1], s0g[g]);                                \
        s1g[g] = mfma_bf16(KC[2], qa[g][0], z);                                     \
        s1g[g] = mfma_bf16(KC[3], qa[g][1], s1g[g]);                                \
    }                                                                               \
    __builtin_amdgcn_s_setprio(0);                                                  \
    KN[0] = ld8(kbase + (size_t)(TN) * DK);                                         \
    KN[1] = ld8(kbase + (size_t)(TN) * DK + 32);                                    \
    KN[2] = ld8(kbase + (size_t)((TN) + 4) * DK);                                   \
    KN[3] = ld8(kbase + (size_t)((TN) + 4) * DK + 32);                              \
    if constexpr (MODE == 1) {                                                      \
        _Pragma("unroll") for (int g = 0; g < 4; g++) {                             \
            MN4[g][0] = *(const ushort4*)(mtb[g] + (TN));                           \
            MN4[g][1] = *(const ushort4*)(mtb[g] + (TN) + 4);                       \
        }                                                                           \
    } else {                                                                        \
        _Pragma("unroll") for (int g = 0; g < 4; g++)                               \
        _Pragma("unroll") for (int st = 0; st < 2; st++)                            \
        _Pragma("unroll") for (int rr = 0; rr < 4; rr++)                            \
            MNF[g][st * 4 + rr] =                                                   \
                mbs[g][(size_t)((TN) + q * 8 + st * 4 + rr) * S_] * msc;            \
    }                                                                               \
    _Pragma("unroll") for (int g = 0; g < 4; g++) {                                 \
        bf16x8 pbv;                                                                 \
        float lsum = 0.f;                                                           \
        _Pragma("unroll") for (int i = 0; i < 8; i++) {                             \
            float sv = (i < 4) ? s0g[g][i & 3] : s1g[g][i & 3];                     \
            float mv;                                                               \
            if constexpr (MODE == 1)                                                \
                mv = bf2f(((const u16*)&MC4[g][i >> 2])[i & 3]);                    \
            else                                                                    \
                mv = MCF[g][i];                                                     \
            float p = __builtin_amdgcn_exp2f(sv + mv);                              \
            lsum += p;                                                              \
            pbv[i] = (__bf16)p;                                                     \
        }                                                                           \
        l_part[g] += lsum;                                                          \
        short8 pa = __builtin_bit_cast(short8, pbv);                                \
        __builtin_amdgcn_s_setprio(1);                                              \
        oacc[g][0] = mfma_bf16(vb0, pa, oacc[g][0]);                                \
        oacc[g][1] = mfma_bf16(vb1, pa, oacc[g][1]);                                \
        oacc[g][2] = mfma_bf16(vb2, pa, oacc[g][2]);                                \
        oacc[g][3] = mfma_bf16(vb3, pa, oacc[g][3]);                                \
        __builtin_amdgcn_s_setprio(0);                                              \
    }                                                                               \
} while (0)

// maskless iteration: V top-loaded (R8 register shape), K ping-pong, no mask loads
#define ATTN_ITER_NM(T0, KC, KN, TN)  do {                                          \
    short8 vb0 = ld8(vbase + (T0));                                                 \
    short8 vb1 = ld8(vbase + 16 * (size_t)T_ + (T0));                               \
    short8 vb2 = ld8(vbase + 32 * (size_t)T_ + (T0));                               \
    short8 vb3 = ld8(vbase + 48 * (size_t)T_ + (T0));                               \
    f32x4 s0g[4], s1g[4];                                                           \
    __builtin_amdgcn_s_setprio(1);                                                  \
    _Pragma("unroll") for (int g = 0; g < 4; g++) {                                 \
        f32x4 z = {};                                                               \
        s0g[g] = mfma_bf16(KC[0], qa[g][0], z);                                     \
        s0g[g] = mfma_bf16(KC[1], qa[g][1], s0g[g]);                                \
        s1g[g] = mfma_bf16(KC[2], qa[g][0], z);                                     \
        s1g[g] = mfma_bf16(KC[3], qa[g][1], s1g[g]);                                \
    }                                                                               \
    __builtin_amdgcn_s_setprio(0);                                                  \
    KN[0] = ld8(kbase + (size_t)(TN) * DK);                                         \
    KN[1] = ld8(kbase + (size_t)(TN) * DK + 32);                                    \
    KN[2] = ld8(kbase + (size_t)((TN) + 4) * DK);                                   \
    KN[3] = ld8(kbase + (size_t)((TN) + 4) * DK + 32);                              \
    _Pragma("unroll") for (int g = 0; g < 4; g++) {                                 \
        bf16x8 pbv;                                                                 \
        float lsum = 0.f;                                                           \
        _Pragma("unroll") for (int i = 0; i < 8; i++) {                             \
            float sv = (i < 4) ? s0g[g][i & 3] : s1g[g][i & 3];                     \
            float p = __builtin_amdgcn_exp2f(sv);                                   \
            lsum += p;                                                              \
            pbv[i] = (__bf16)p;                                                     \
        }                                                                           \
        l_part[g] += lsum;                                                          \
        short8 pa = __builtin_bit_cast(short8, pbv);                                \
        __builtin_amdgcn_s_setprio(1);                                              \
        oacc[g][0] = mfma_bf16(vb0, pa, oacc[g][0]);                                \
        oacc[g][1] = mfma_bf16(vb1, pa, oacc[g][1]);                                \
        oacc[g][2] = mfma_bf16(vb2, pa, oacc[g][2]);                                \
        oacc[g][3] = mfma_bf16(vb3, pa, oacc[g][3]);                                \
        __builtin_amdgcn_s_setprio(0);                                              \
    }                                                                               \
} while (0)

template<int MODE>
__global__ __launch_bounds__(512, 2) void k_attn(const u16* __restrict__ kt, const u16* __restrict__ qt,
                                                 const u16* __restrict__ vt, const float* __restrict__ mask,
                                                 const u16* __restrict__ mt, const u32* __restrict__ mflag,
                                                 u16* __restrict__ oa) {
    __shared__ struct { float O[8][16][68]; float L[8][16]; } Sm;   // 35328 B, merge only
    int wv = threadIdx.x >> 6, lane = threadIdx.x & 63;
    int col = lane & 15, q = lane >> 4;
    // XCD-local decode: blocks with blockIdx%8==x cover bh {2x,2x+1}
    int bid = blockIdx.x;
    int j = bid >> 3;
    int bh = (bid & 7) * 2 + (j >> 5);
    int s_base = (j & 31) * 64;
    int sg = s_base + col;
    const int t_begin = wv * (T_ / 8);
    const int t_end = t_begin + (T_ / 8);
    short8 qa[4][2];
#pragma unroll
    for (int g = 0; g < 4; g++) {
        const u16* qp = qt + (size_t)(bh * S_ + sg + g * 16) * DK + q * 8;
        qa[g][0] = ld8(qp);
        qa[g][1] = ld8(qp + 32);
    }
    // K rows permuted so QK output lands in PV B-operand layout
    int tperm = ((col >> 2) << 3) | (col & 3);
    const u16* kbase = kt + (size_t)bh * T_ * DK + (size_t)tperm * DK + q * 8;
    const u16* vbase = vt + (size_t)bh * DK * T_ + (size_t)col * T_ + q * 8;
    float l_part[4] = {0.f, 0.f, 0.f, 0.f};
    f32x4 oacc[4][4] = {};
    const float msc = 0.180336880f;   // 0.125 * log2(e), for the f32-mask fallback

    int use_mask = mflag ? (int)*mflag : 1;

    if (use_mask == 0) {
        // ---- maskless path (mask verified all-zero): no MT loads, V top-loaded ----
        short8 kA[4], kB[4];
        kA[0] = ld8(kbase + (size_t)t_begin * DK);
        kA[1] = ld8(kbase + (size_t)t_begin * DK + 32);
        kA[2] = ld8(kbase + (size_t)(t_begin + 4) * DK);
        kA[3] = ld8(kbase + (size_t)(t_begin + 4) * DK + 32);
        for (int t0 = t_begin; t0 < t_end; t0 += 64) {
            ATTN_ITER_NM(t0, kA, kB, t0 + 32);
            int tn2 = (t0 + 64 < t_end) ? (t0 + 64) : t_begin;   // clamp: last prefetch unused
            ATTN_ITER_NM(t0 + 32, kB, kA, tn2);
        }
    } else {
        // ---- masked path (general correctness; R8 structure) ----
        const float* mbs[4];
        const u16* mtb[4];
#pragma unroll
        for (int g = 0; g < 4; g++) {
            mbs[g] = mask + sg + g * 16;
            mtb[g] = mt + (size_t)(sg + g * 16) * T_ + q * 8;
        }
        short8 kA[4], kB[4];
        ushort4 mA4[4][2], mB4[4][2];
        float mAf[4][8], mBf[4][8];
        kA[0] = ld8(kbase + (size_t)t_begin * DK);
        kA[1] = ld8(kbase + (size_t)t_begin * DK + 32);
        kA[2] = ld8(kbase + (size_t)(t_begin + 4) * DK);
        kA[3] = ld8(kbase + (size_t)(t_begin + 4) * DK + 32);
        if constexpr (MODE == 1) {
#pragma unroll
            for (int g = 0; g < 4; g++) {
                mA4[g][0] = *(const ushort4*)(mtb[g] + t_begin);
                mA4[g][1] = *(const ushort4*)(mtb[g] + t_begin + 4);
            }
        } else {
#pragma unroll
            for (int g = 0; g < 4; g++)
#pragma unroll
                for (int st = 0; st < 2; st++)
#pragma unroll
                    for (int rr = 0; rr < 4; rr++)
                        mAf[g][st * 4 + rr] =
                            mbs[g][(size_t)(t_begin + q * 8 + st * 4 + rr) * S_] * msc;
        }
        for (int t0 = t_begin; t0 < t_end; t0 += 64) {
            ATTN_ITER_M(t0, kA, mA4, mAf, kB, mB4, mBf, t0 + 32);
            int tn2 = (t0 + 64 < t_end) ? (t0 + 64) : t_begin;
            ATTN_ITER_M(t0 + 32, kB, mB4, mBf, kA, mA4, mAf, tn2);
        }
    }

    // l: reduce per-lane partials over q (per-s totals, uniform across q-lanes)
#pragma unroll
    for (int g = 0; g < 4; g++) {
        float lr = l_part[g];
        lr += __shfl_xor(lr, 16);
        lr += __shfl_xor(lr, 32);
        l_part[g] = lr;
    }

    // ---- merge of the 8 per-wave T-partials: O = Sum(O_c) / Sum(l_c), per 16-s group ----
    int b = bh >> 3, h = bh & 7;
    __syncthreads();
#pragma unroll
    for (int g = 0; g < 4; g++) {
#pragma unroll
        for (int nt = 0; nt < 4; nt++)
            *(f32x4*)&Sm.O[wv][col][nt * 16 + q * 4] = oacc[g][nt];
        if (lane < 16)
            Sm.L[wv][lane] = l_part[g];
        __syncthreads();
        // 1024 outputs (16 s x 64 v), 512 threads -> 2 each
#pragma unroll
        for (int e = 0; e < 2; e++) {
            int f = (int)threadIdx.x + e * 512;
            int s = f >> 6, v = f & 63;
            float acc = 0.f, lt = 0.f;
#pragma unroll
            for (int c = 0; c < 8; c++) {
                acc += Sm.O[c][s][v];
                lt += Sm.L[c][s];
            }
            oa[(size_t)(b * S_ + s_base + g * 16 + s) * E_ + h * DK + v] = f2bf(acc / lt);
        }
        __syncthreads();   // O/L reused by next group
    }
}

// ---------------- final GEMM (32x64 tiles, pipelined): out[b][s][o] = OA . W + bias ----------------
// block tile 32s x 64o (grid 1024 = 4 blocks/CU, 16 waves/CU), wave tile 16s x 32o
__global__ __launch_bounds__(256) void k_final(const u16* __restrict__ oa, const u16* __restrict__ wfb,
                                               const float* __restrict__ bias, float* __restrict__ out) {
    int bi = blockIdx.x;
    int et = bi & 7, tt = bi >> 3;        // et: 64-o tile (8), tt: 32-s tile (128, b folded)
    int wv = threadIdx.x >> 6, lane = threadIdx.x & 63;
    int col = lane & 15, q = lane >> 4;
    int b = tt >> 6;
    int s0 = (tt & 63) * 32 + (wv >> 1) * 16;
    int o0 = et * 64 + (wv & 1) * 32;
    const u16* ap0 = oa + (size_t)(b * S_ + s0 + col) * E_ + q * 8;
    const u16* bp0 = wfb + (size_t)(o0 + col) * E_ + q * 8;
    f32x4 acc[2] = {};
    short8 a0 = ld8(ap0);
    short8 b0 = ld8(bp0), b1 = ld8(bp0 + 16 * E_);
#pragma unroll
    for (int ks = 0; ks < 16; ks++) {
        short8 na0, nb0, nb1;
        if (ks < 15) {
            na0 = ld8(ap0 + (ks + 1) * 32);
            nb0 = ld8(bp0 + (ks + 1) * 32);
            nb1 = ld8(bp0 + 16 * E_ + (ks + 1) * 32);
        }
        acc[0] = mfma_bf16(a0, b0, acc[0]);
        acc[1] = mfma_bf16(a0, b1, acc[1]);
        if (ks < 15) {
            a0 = na0; b0 = nb0; b1 = nb1;
        }
    }
#pragma unroll
    for (int nt = 0; nt < 2; nt++) {
        int o = o0 + nt * 16 + col;
        float bn = bias[o];
#pragma unroll
        for (int r = 0; r < 4; r++) {
            int s = s0 + q * 4 + r;
            out[(size_t)(b * S_ + s) * CO + o] = acc[nt][r] + bn;
        }
    }
}

extern "C" void kernel_launch(void* const* d_in, const int* in_sizes, int n_in,
                              void* d_out, int out_size, void* d_ws, size_t ws_size,
                              hipStream_t stream) {
    const float* x    = (const float*)d_in[0];
    const float* y    = (const float*)d_in[1];
    const float* mask = (const float*)d_in[2];
    const float* Wk   = (const float*)d_in[3];
    const float* Wv   = (const float*)d_in[4];
    const float* Wq   = (const float*)d_in[5];
    const float* Wf   = (const float*)d_in[6];
    const float* bias = (const float*)d_in[7];
    float* out = (float*)d_out;

    // Layout (u16 units): 18 MiB core + 8 MiB MT + 4 MiB separate VT + mask flag.
    u16* ws = (u16*)d_ws;
    u16* XT  = ws;                 // x^T bf16; reused as OA after projections
    u16* YT  = XT + 2097152;       // y^T bf16; fallback VT alias
    u16* WKB = YT + 2097152;
    u16* WVB = WKB + 262144;
    u16* WQB = WVB + 262144;
    u16* WFB = WQB + 262144;
    u16* KT  = WFB + 262144;
    u16* QT  = KT + 2097152;       // end = 18 MiB
    u16* MT  = QT + 2097152;       // mask^T bf16 pre-scaled, end = 26 MiB
    u16* VTs = MT + 4194304;       // separate V, end = 30 MiB
    u32* MF  = (u32*)(VTs + 2097152);  // mask-nonzero flag, at 30 MiB
    u16* OA  = XT;                 // alias: XT dead after K/V proj

    int use_mt   = (ws_size >= (size_t)27262976) ? 1 : 0;   // 26 MiB for MT
    int has_vt   = (ws_size >= (size_t)31457280) ? 1 : 0;   // 30 MiB for separate VT
    int has_flag = (ws_size >= (size_t)31457344) ? 1 : 0;   // 30 MiB + flag word
    u16* VT = has_vt ? VTs : YT;
    u32* MFp = (use_mt && has_flag) ? MF : (u32*)nullptr;

    if (MFp)
        hipMemsetAsync(MFp, 0, 4, stream);
    // single prep launch: transpose (4096 blocks) + weight cvt (512) + mask^T (4096)
    k_prep<<<use_mt ? 8704 : 4608, 256, 0, stream>>>(x, y, Wk, Wv, Wq, Wf, mask,
                                                     XT, YT, WKB, WVB, WQB, WFB, MT, MFp);
    if (has_vt) {
        // single fused launch: Q (reads YT), K, V (writes separate VTs)
        k_proj3<<<1536, 256, 0, stream>>>(XT, YT, WKB, WVB, WQB, KT, VT, QT, 0);
    } else {
        // launch 1: Q (reads YT) + K; launch 2: V (writes VT == YT, safe after launch 1)
        k_proj3<<<1024, 256, 0, stream>>>(XT, YT, WKB, WVB, WQB, KT, VT, QT, 0);
        k_proj3<<<512, 256, 0, stream>>>(XT, YT, WKB, WVB, WQB, KT, VT, QT, 2);
    }
    if (use_mt)
        k_attn<1><<<512, 512, 0, stream>>>(KT, QT, VT, mask, MT, MFp, OA);
    else
        k_attn<0><<<512, 512, 0, stream>>>(KT, QT, VT, mask, MT, MFp, OA);
    k_final<<<1024, 256, 0, stream>>>(OA, WFB, bias, out);
}

// Round 14
// 194.986 us; speedup vs baseline: 1.0880x; 1.0880x over previous
//
#include <hip/hip_runtime.h>
#include <stdint.h>

typedef unsigned short u16;
typedef unsigned int u32;

#define B_    2
#define DK    64
#define T_    2048
#define S_    2048
#define CI    512
#define CO    512
#define E_    512

typedef short  short8 __attribute__((ext_vector_type(8)));
typedef __bf16 bf16x8 __attribute__((ext_vector_type(8)));
typedef float  f32x4  __attribute__((ext_vector_type(4)));

static __device__ __forceinline__ u16 f2bf(float f) {
    return __builtin_bit_cast(u16, (__bf16)f);
}

static __device__ __forceinline__ float bf2f(u16 h) {
    return __uint_as_float((u32)h << 16);
}

static __device__ __forceinline__ short8 ld8(const u16* p) {
    return *(const short8*)p;
}

static __device__ __forceinline__ f32x4 mfma_bf16(short8 a, short8 b, f32x4 c) {
    return __builtin_amdgcn_mfma_f32_16x16x32_bf16(
        __builtin_bit_cast(bf16x8, a), __builtin_bit_cast(bf16x8, b), c, 0, 0, 0);
}

// ---------------- fused prep: x/y transpose + weight cvt + mask^T (+nonzero detect) ----------------
__global__ __launch_bounds__(256) void k_prep(const float* __restrict__ x, const float* __restrict__ y,
                                              const float* __restrict__ wk, const float* __restrict__ wv,
                                              const float* __restrict__ wq, const float* __restrict__ wf,
                                              const float* __restrict__ mask,
                                              u16* __restrict__ xt, u16* __restrict__ yt,
                                              u16* __restrict__ wkb, u16* __restrict__ wvb,
                                              u16* __restrict__ wqb, u16* __restrict__ wfb,
                                              u16* __restrict__ mt, u32* __restrict__ mflag) {
    __shared__ float tile[32][33];
    int bid = blockIdx.x;
    if (bid < 4096) {
        // transpose + cvt: src[b][i][t] f32 -> dst[b][t][i] bf16
        int bx = bid & 63, by = (bid >> 6) & 15, bz = bid >> 10;
        int tsel = bz >> 1, b = bz & 1;
        const float* src = tsel ? y : x;
        u16* dst = tsel ? yt : xt;
        int t0 = bx * 32, i0 = by * 32;
        int tx = threadIdx.x & 31, ty = threadIdx.x >> 5;
#pragma unroll
        for (int r = 0; r < 4; r++)
            tile[ty + r * 8][tx] = src[(size_t)(b * CI + i0 + ty + r * 8) * T_ + t0 + tx];
        __syncthreads();
#pragma unroll
        for (int r = 0; r < 4; r++)
            dst[(size_t)(b * T_ + t0 + ty + r * 8) * CI + i0 + tx] = f2bf(tile[tx][ty + r * 8]);
    } else if (bid < 4608) {
        // weight cvt, 8 elems/thread (512 blocks x 256 thr x 8 = 1M elems)
        int off = ((bid - 4096) * 256 + threadIdx.x) * 8;
        int w = off >> 18, r = off & 262143;
        const float* s = (w == 0) ? wk : (w == 1) ? wv : (w == 2) ? wq : wf;
        u16* d = (w == 0) ? wkb : (w == 1) ? wvb : (w == 2) ? wqb : wfb;
        float4 a0 = *(const float4*)(s + r);
        float4 a1 = *(const float4*)(s + r + 4);
        short8 o;
        o[0] = f2bf(a0.x); o[1] = f2bf(a0.y); o[2] = f2bf(a0.z); o[3] = f2bf(a0.w);
        o[4] = f2bf(a1.x); o[5] = f2bf(a1.y); o[6] = f2bf(a1.z); o[7] = f2bf(a1.w);
        *(short8*)(d + r) = o;
    } else {
        // mask transpose + pre-scale: mask[t][s] f32 -> mt[s][t] bf16*msc; detect any-nonzero
        int mb = bid - 4608;
        int t0 = (mb & 63) * 32, s0 = (mb >> 6) * 32;
        int tx = threadIdx.x & 31, ty = threadIdx.x >> 5;
        const float msc = 0.125f * 1.44269504088896f;
        bool nz = false;
#pragma unroll
        for (int r = 0; r < 4; r++) {
            float v = mask[(size_t)(t0 + ty + r * 8) * S_ + s0 + tx];
            tile[ty + r * 8][tx] = v;
            nz |= (v != 0.0f);
        }
        if (mflag && __any(nz) && (threadIdx.x & 63) == 0)
            atomicOr(mflag, 1u);
        __syncthreads();
#pragma unroll
        for (int r = 0; r < 4; r++)
            mt[(size_t)(s0 + ty + r * 8) * T_ + t0 + tx] = f2bf(tile[tx][ty + r * 8] * msc);
    }
}

// ---------------- fused projection GEMMs (R11 geometry: 64t x 128e, pipelined) ----------------
// R13 post-mortem: 64x64 retile cut per-wave operand reuse (0.75 -> 1.0 loads/MFMA)
// and regressed ~17us. Reverted to the R11-measured shape: block 64t x 128e,
// wave 32t x 64e, grid 768 fused (3 blocks/CU).
// p = p_base + (blockIdx.x>>8): 0=Q (yt->QT, pre-scaled by sc), 1=K, 2=V.
__global__ __launch_bounds__(256) void k_proj3(const u16* __restrict__ xt, const u16* __restrict__ yt,
                                               const u16* __restrict__ wkb, const u16* __restrict__ wvb,
                                               const u16* __restrict__ wqb,
                                               u16* __restrict__ ktd, u16* __restrict__ vtd,
                                               u16* __restrict__ qtd, int p_base) {
    int bi = blockIdx.x;
    int p = p_base + (bi >> 8);
    int r = bi & 255;
    int et = r & 3, tt = r >> 2;          // et: 128-e tile, tt: 64-t tile (b folded)
    int wv = threadIdx.x >> 6, lane = threadIdx.x & 63;
    int col = lane & 15, q = lane >> 4;
    int b = tt >> 5;
    int t0 = (tt & 31) * 64 + (wv >> 1) * 32;
    int e0 = et * 128 + (wv & 1) * 64;
    const u16* src = (p == 0) ? yt : xt;
    const u16* wb  = (p == 0) ? wqb : (p == 1) ? wkb : wvb;
    const u16* ap0 = src + (size_t)(b * T_ + t0 + col) * CI + q * 8;
    const u16* bp0 = wb + (size_t)(e0 + col) * CI + q * 8;
    f32x4 acc[2][4] = {};
    short8 a0 = ld8(ap0), a1 = ld8(ap0 + 16 * CI);
    short8 b0 = ld8(bp0), b1 = ld8(bp0 + 16 * CI);
    short8 b2 = ld8(bp0 + 32 * CI), b3 = ld8(bp0 + 48 * CI);
#pragma unroll
    for (int ks = 0; ks < 16; ks++) {
        short8 na0, na1, nb0, nb1, nb2, nb3;
        if (ks < 15) {
            na0 = ld8(ap0 + (ks + 1) * 32);
            na1 = ld8(ap0 + 16 * CI + (ks + 1) * 32);
            nb0 = ld8(bp0 + (ks + 1) * 32);
            nb1 = ld8(bp0 + 16 * CI + (ks + 1) * 32);
            nb2 = ld8(bp0 + 32 * CI + (ks + 1) * 32);
            nb3 = ld8(bp0 + 48 * CI + (ks + 1) * 32);
        }
        acc[0][0] = mfma_bf16(a0, b0, acc[0][0]); acc[1][0] = mfma_bf16(a1, b0, acc[1][0]);
        acc[0][1] = mfma_bf16(a0, b1, acc[0][1]); acc[1][1] = mfma_bf16(a1, b1, acc[1][1]);
        acc[0][2] = mfma_bf16(a0, b2, acc[0][2]); acc[1][2] = mfma_bf16(a1, b2, acc[1][2]);
        acc[0][3] = mfma_bf16(a0, b3, acc[0][3]); acc[1][3] = mfma_bf16(a1, b3, acc[1][3]);
        if (ks < 15) {
            a0 = na0; a1 = na1; b0 = nb0; b1 = nb1; b2 = nb2; b3 = nb3;
        }
    }
    // Q gets the softmax scale folded in (sc = 0.125 * log2(e)); K/V unscaled.
    float qs = (p == 0) ? 0.180336880f : 1.0f;
    u16* dst = (p == 0) ? qtd : (p == 1) ? ktd : vtd;
    if (p < 2) {
#pragma unroll
        for (int mt = 0; mt < 2; mt++)
#pragma unroll
            for (int nt = 0; nt < 4; nt++) {
                int e = e0 + nt * 16 + col, h = e >> 6, k = e & 63;
                u16* dp = dst + ((size_t)(b * 8 + h) * T_ + t0 + mt * 16 + q * 4) * DK + k;
                dp[0] = f2bf(acc[mt][nt][0] * qs);
                dp[DK] = f2bf(acc[mt][nt][1] * qs);
                dp[2 * DK] = f2bf(acc[mt][nt][2] * qs);
                dp[3 * DK] = f2bf(acc[mt][nt][3] * qs);
            }
    } else {
#pragma unroll
        for (int mt = 0; mt < 2; mt++)
#pragma unroll
            for (int nt = 0; nt < 4; nt++) {
                int e = e0 + nt * 16 + col, h = e >> 6, v = e & 63;
                uint2 pk;
                pk.x = f2bf(acc[mt][nt][0]) | ((u32)f2bf(acc[mt][nt][1]) << 16);
                pk.y = f2bf(acc[mt][nt][2]) | ((u32)f2bf(acc[mt][nt][3]) << 16);
                *(uint2*)(dst + ((size_t)(b * 8 + h) * DK + v) * T_ + t0 + mt * 16 + q * 4) = pk;
            }
    }
}

// ---------------- flash attention: runtime mask-skip, barrier-free inner loop ----------------
// R13 measured: maskless path (V top-loaded, K ping-pong, no MT loads) = 52.5us,
// FETCH 10.3MB. Kept verbatim. Masked path (general correctness) = R8 structure.

// masked iteration (mv pre-scaled, Q pre-scaled -> add)
#define ATTN_ITER_M(T0, KC, MC4, MCF, KN, MN4, MNF, TN)  do {                       \
    short8 vb0 = ld8(vbase + (T0));                                                 \
    short8 vb1 = ld8(vbase + 16 * (size_t)T_ + (T0));                               \
    short8 vb2 = ld8(vbase + 32 * (size_t)T_ + (T0));                               \
    short8 vb3 = ld8(vbase + 48 * (size_t)T_ + (T0));                               \
    f32x4 s0g[4], s1g[4];                                                           \
    __builtin_amdgcn_s_setprio(1);                                                  \
    _Pragma("unroll") for (int g = 0; g < 4; g++) {                                 \
        f32x4 z = {};                                                               \
        s0g[g] = mfma_bf16(KC[0], qa[g][0], z);                                     \
        s0g[g] = mfma_bf16(KC[1], qa[g][1], s0g[g]);                                \
        s1g[g] = mfma_bf16(KC[2], qa[g][0], z);                                     \
        s1g[g] = mfma_bf16(KC[3], qa[g][1], s1g[g]);                                \
    }                                                                               \
    __builtin_amdgcn_s_setprio(0);                                                  \
    KN[0] = ld8(kbase + (size_t)(TN) * DK);                                         \
    KN[1] = ld8(kbase + (size_t)(TN) * DK + 32);                                    \
    KN[2] = ld8(kbase + (size_t)((TN) + 4) * DK);                                   \
    KN[3] = ld8(kbase + (size_t)((TN) + 4) * DK + 32);                              \
    if constexpr (MODE == 1) {                                                      \
        _Pragma("unroll") for (int g = 0; g < 4; g++) {                             \
            MN4[g][0] = *(const ushort4*)(mtb[g] + (TN));                           \
            MN4[g][1] = *(const ushort4*)(mtb[g] + (TN) + 4);                       \
        }                                                                           \
    } else {                                                                        \
        _Pragma("unroll") for (int g = 0; g < 4; g++)                               \
        _Pragma("unroll") for (int st = 0; st < 2; st++)                            \
        _Pragma("unroll") for (int rr = 0; rr < 4; rr++)                            \
            MNF[g][st * 4 + rr] =                                                   \
                mbs[g][(size_t)((TN) + q * 8 + st * 4 + rr) * S_] * msc;            \
    }                                                                               \
    _Pragma("unroll") for (int g = 0; g < 4; g++) {                                 \
        bf16x8 pbv;                                                                 \
        float lsum = 0.f;                                                           \
        _Pragma("unroll") for (int i = 0; i < 8; i++) {                             \
            float sv = (i < 4) ? s0g[g][i & 3] : s1g[g][i & 3];                     \
            float mv;                                                               \
            if constexpr (MODE == 1)                                                \
                mv = bf2f(((const u16*)&MC4[g][i >> 2])[i & 3]);                    \
            else                                                                    \
                mv = MCF[g][i];                                                     \
            float p = __builtin_amdgcn_exp2f(sv + mv);                              \
            lsum += p;                                                              \
            pbv[i] = (__bf16)p;                                                     \
        }                                                                           \
        l_part[g] += lsum;                                                          \
        short8 pa = __builtin_bit_cast(short8, pbv);                                \
        __builtin_amdgcn_s_setprio(1);                                              \
        oacc[g][0] = mfma_bf16(vb0, pa, oacc[g][0]);                                \
        oacc[g][1] = mfma_bf16(vb1, pa, oacc[g][1]);                                \
        oacc[g][2] = mfma_bf16(vb2, pa, oacc[g][2]);                                \
        oacc[g][3] = mfma_bf16(vb3, pa, oacc[g][3]);                                \
        __builtin_amdgcn_s_setprio(0);                                              \
    }                                                                               \
} while (0)

// maskless iteration: V top-loaded (R8 register shape), K ping-pong, no mask loads
#define ATTN_ITER_NM(T0, KC, KN, TN)  do {                                          \
    short8 vb0 = ld8(vbase + (T0));                                                 \
    short8 vb1 = ld8(vbase + 16 * (size_t)T_ + (T0));                               \
    short8 vb2 = ld8(vbase + 32 * (size_t)T_ + (T0));                               \
    short8 vb3 = ld8(vbase + 48 * (size_t)T_ + (T0));                               \
    f32x4 s0g[4], s1g[4];                                                           \
    __builtin_amdgcn_s_setprio(1);                                                  \
    _Pragma("unroll") for (int g = 0; g < 4; g++) {                                 \
        f32x4 z = {};                                                               \
        s0g[g] = mfma_bf16(KC[0], qa[g][0], z);                                     \
        s0g[g] = mfma_bf16(KC[1], qa[g][1], s0g[g]);                                \
        s1g[g] = mfma_bf16(KC[2], qa[g][0], z);                                     \
        s1g[g] = mfma_bf16(KC[3], qa[g][1], s1g[g]);                                \
    }                                                                               \
    __builtin_amdgcn_s_setprio(0);                                                  \
    KN[0] = ld8(kbase + (size_t)(TN) * DK);                                         \
    KN[1] = ld8(kbase + (size_t)(TN) * DK + 32);                                    \
    KN[2] = ld8(kbase + (size_t)((TN) + 4) * DK);                                   \
    KN[3] = ld8(kbase + (size_t)((TN) + 4) * DK + 32);                              \
    _Pragma("unroll") for (int g = 0; g < 4; g++) {                                 \
        bf16x8 pbv;                                                                 \
        float lsum = 0.f;                                                           \
        _Pragma("unroll") for (int i = 0; i < 8; i++) {                             \
            float sv = (i < 4) ? s0g[g][i & 3] : s1g[g][i & 3];                     \
            float p = __builtin_amdgcn_exp2f(sv);                                   \
            lsum += p;                                                              \
            pbv[i] = (__bf16)p;                                                     \
        }                                                                           \
        l_part[g] += lsum;                                                          \
        short8 pa = __builtin_bit_cast(short8, pbv);                                \
        __builtin_amdgcn_s_setprio(1);                                              \
        oacc[g][0] = mfma_bf16(vb0, pa, oacc[g][0]);                                \
        oacc[g][1] = mfma_bf16(vb1, pa, oacc[g][1]);                                \
        oacc[g][2] = mfma_bf16(vb2, pa, oacc[g][2]);                                \
        oacc[g][3] = mfma_bf16(vb3, pa, oacc[g][3]);                                \
        __builtin_amdgcn_s_setprio(0);                                              \
    }                                                                               \
} while (0)

template<int MODE>
__global__ __launch_bounds__(512, 2) void k_attn(const u16* __restrict__ kt, const u16* __restrict__ qt,
                                                 const u16* __restrict__ vt, const float* __restrict__ mask,
                                                 const u16* __restrict__ mt, const u32* __restrict__ mflag,
                                                 u16* __restrict__ oa) {
    __shared__ struct { float O[8][16][68]; float L[8][16]; } Sm;   // 35328 B, merge only
    int wv = threadIdx.x >> 6, lane = threadIdx.x & 63;
    int col = lane & 15, q = lane >> 4;
    // XCD-local decode: blocks with blockIdx%8==x cover bh {2x,2x+1}
    int bid = blockIdx.x;
    int j = bid >> 3;
    int bh = (bid & 7) * 2 + (j >> 5);
    int s_base = (j & 31) * 64;
    int sg = s_base + col;
    const int t_begin = wv * (T_ / 8);
    const int t_end = t_begin + (T_ / 8);
    short8 qa[4][2];
#pragma unroll
    for (int g = 0; g < 4; g++) {
        const u16* qp = qt + (size_t)(bh * S_ + sg + g * 16) * DK + q * 8;
        qa[g][0] = ld8(qp);
        qa[g][1] = ld8(qp + 32);
    }
    // K rows permuted so QK output lands in PV B-operand layout
    int tperm = ((col >> 2) << 3) | (col & 3);
    const u16* kbase = kt + (size_t)bh * T_ * DK + (size_t)tperm * DK + q * 8;
    const u16* vbase = vt + (size_t)bh * DK * T_ + (size_t)col * T_ + q * 8;
    float l_part[4] = {0.f, 0.f, 0.f, 0.f};
    f32x4 oacc[4][4] = {};
    const float msc = 0.180336880f;   // 0.125 * log2(e), for the f32-mask fallback

    int use_mask = mflag ? (int)*mflag : 1;

    if (use_mask == 0) {
        // ---- maskless path (mask verified all-zero): no MT loads, V top-loaded ----
        short8 kA[4], kB[4];
        kA[0] = ld8(kbase + (size_t)t_begin * DK);
        kA[1] = ld8(kbase + (size_t)t_begin * DK + 32);
        kA[2] = ld8(kbase + (size_t)(t_begin + 4) * DK);
        kA[3] = ld8(kbase + (size_t)(t_begin + 4) * DK + 32);
        for (int t0 = t_begin; t0 < t_end; t0 += 64) {
            ATTN_ITER_NM(t0, kA, kB, t0 + 32);
            int tn2 = (t0 + 64 < t_end) ? (t0 + 64) : t_begin;   // clamp: last prefetch unused
            ATTN_ITER_NM(t0 + 32, kB, kA, tn2);
        }
    } else {
        // ---- masked path (general correctness; R8 structure) ----
        const float* mbs[4];
        const u16* mtb[4];
#pragma unroll
        for (int g = 0; g < 4; g++) {
            mbs[g] = mask + sg + g * 16;
            mtb[g] = mt + (size_t)(sg + g * 16) * T_ + q * 8;
        }
        short8 kA[4], kB[4];
        ushort4 mA4[4][2], mB4[4][2];
        float mAf[4][8], mBf[4][8];
        kA[0] = ld8(kbase + (size_t)t_begin * DK);
        kA[1] = ld8(kbase + (size_t)t_begin * DK + 32);
        kA[2] = ld8(kbase + (size_t)(t_begin + 4) * DK);
        kA[3] = ld8(kbase + (size_t)(t_begin + 4) * DK + 32);
        if constexpr (MODE == 1) {
#pragma unroll
            for (int g = 0; g < 4; g++) {
                mA4[g][0] = *(const ushort4*)(mtb[g] + t_begin);
                mA4[g][1] = *(const ushort4*)(mtb[g] + t_begin + 4);
            }
        } else {
#pragma unroll
            for (int g = 0; g < 4; g++)
#pragma unroll
                for (int st = 0; st < 2; st++)
#pragma unroll
                    for (int rr = 0; rr < 4; rr++)
                        mAf[g][st * 4 + rr] =
                            mbs[g][(size_t)(t_begin + q * 8 + st * 4 + rr) * S_] * msc;
        }
        for (int t0 = t_begin; t0 < t_end; t0 += 64) {
            ATTN_ITER_M(t0, kA, mA4, mAf, kB, mB4, mBf, t0 + 32);
            int tn2 = (t0 + 64 < t_end) ? (t0 + 64) : t_begin;
            ATTN_ITER_M(t0 + 32, kB, mB4, mBf, kA, mA4, mAf, tn2);
        }
    }

    // l: reduce per-lane partials over q (per-s totals, uniform across q-lanes)
#pragma unroll
    for (int g = 0; g < 4; g++) {
        float lr = l_part[g];
        lr += __shfl_xor(lr, 16);
        lr += __shfl_xor(lr, 32);
        l_part[g] = lr;
    }

    // ---- merge of the 8 per-wave T-partials: O = Sum(O_c) / Sum(l_c), per 16-s group ----
    int b = bh >> 3, h = bh & 7;
    __syncthreads();
#pragma unroll
    for (int g = 0; g < 4; g++) {
#pragma unroll
        for (int nt = 0; nt < 4; nt++)
            *(f32x4*)&Sm.O[wv][col][nt * 16 + q * 4] = oacc[g][nt];
        if (lane < 16)
            Sm.L[wv][lane] = l_part[g];
        __syncthreads();
        // 1024 outputs (16 s x 64 v), 512 threads -> 2 each
#pragma unroll
        for (int e = 0; e < 2; e++) {
            int f = (int)threadIdx.x + e * 512;
            int s = f >> 6, v = f & 63;
            float acc = 0.f, lt = 0.f;
#pragma unroll
            for (int c = 0; c < 8; c++) {
                acc += Sm.O[c][s][v];
                lt += Sm.L[c][s];
            }
            oa[(size_t)(b * S_ + s_base + g * 16 + s) * E_ + h * DK + v] = f2bf(acc / lt);
        }
        __syncthreads();   // O/L reused by next group
    }
}

// ---------------- final GEMM (R11 geometry: 64s x 64o, grid 512, pipelined) ----------------
// wave tile 32s x 32o
__global__ __launch_bounds__(256) void k_final(const u16* __restrict__ oa, const u16* __restrict__ wfb,
                                               const float* __restrict__ bias, float* __restrict__ out) {
    int bi = blockIdx.x;
    int et = bi & 7, tt = bi >> 3;
    int wv = threadIdx.x >> 6, lane = threadIdx.x & 63;
    int col = lane & 15, q = lane >> 4;
    int b = tt >> 5;
    int s0 = (tt & 31) * 64 + (wv >> 1) * 32;
    int o0 = et * 64 + (wv & 1) * 32;
    const u16* ap0 = oa + (size_t)(b * S_ + s0 + col) * E_ + q * 8;
    const u16* bp0 = wfb + (size_t)(o0 + col) * E_ + q * 8;
    f32x4 acc[2][2] = {};
    short8 a0 = ld8(ap0), a1 = ld8(ap0 + 16 * E_);
    short8 b0 = ld8(bp0), b1 = ld8(bp0 + 16 * E_);
#pragma unroll
    for (int ks = 0; ks < 16; ks++) {
        short8 na0, na1, nb0, nb1;
        if (ks < 15) {
            na0 = ld8(ap0 + (ks + 1) * 32);
            na1 = ld8(ap0 + 16 * E_ + (ks + 1) * 32);
            nb0 = ld8(bp0 + (ks + 1) * 32);
            nb1 = ld8(bp0 + 16 * E_ + (ks + 1) * 32);
        }
        acc[0][0] = mfma_bf16(a0, b0, acc[0][0]); acc[1][0] = mfma_bf16(a1, b0, acc[1][0]);
        acc[0][1] = mfma_bf16(a0, b1, acc[0][1]); acc[1][1] = mfma_bf16(a1, b1, acc[1][1]);
        if (ks < 15) {
            a0 = na0; a1 = na1; b0 = nb0; b1 = nb1;
        }
    }
#pragma unroll
    for (int mt = 0; mt < 2; mt++)
#pragma unroll
        for (int nt = 0; nt < 2; nt++) {
            int o = o0 + nt * 16 + col;
            float bn = bias[o];
#pragma unroll
            for (int r = 0; r < 4; r++) {
                int s = s0 + mt * 16 + q * 4 + r;
                out[(size_t)(b * S_ + s) * CO + o] = acc[mt][nt][r] + bn;
            }
        }
}

extern "C" void kernel_launch(void* const* d_in, const int* in_sizes, int n_in,
                              void* d_out, int out_size, void* d_ws, size_t ws_size,
                              hipStream_t stream) {
    const float* x    = (const float*)d_in[0];
    const float* y    = (const float*)d_in[1];
    const float* mask = (const float*)d_in[2];
    const float* Wk   = (const float*)d_in[3];
    const float* Wv   = (const float*)d_in[4];
    const float* Wq   = (const float*)d_in[5];
    const float* Wf   = (const float*)d_in[6];
    const float* bias = (const float*)d_in[7];
    float* out = (float*)d_out;

    // Layout (u16 units): 18 MiB core + 8 MiB MT + 4 MiB separate VT + mask flag.
    u16* ws = (u16*)d_ws;
    u16* XT  = ws;                 // x^T bf16; reused as OA after projections
    u16* YT  = XT + 2097152;       // y^T bf16; fallback VT alias
    u16* WKB = YT + 2097152;
    u16* WVB = WKB + 262144;
    u16* WQB = WVB + 262144;
    u16* WFB = WQB + 262144;
    u16* KT  = WFB + 262144;
    u16* QT  = KT + 2097152;       // end = 18 MiB
    u16* MT  = QT + 2097152;       // mask^T bf16 pre-scaled, end = 26 MiB
    u16* VTs = MT + 4194304;       // separate V, end = 30 MiB
    u32* MF  = (u32*)(VTs + 2097152);  // mask-nonzero flag, at 30 MiB
    u16* OA  = XT;                 // alias: XT dead after K/V proj

    int use_mt   = (ws_size >= (size_t)27262976) ? 1 : 0;   // 26 MiB for MT
    int has_vt   = (ws_size >= (size_t)31457280) ? 1 : 0;   // 30 MiB for separate VT
    int has_flag = (ws_size >= (size_t)31457344) ? 1 : 0;   // 30 MiB + flag word
    u16* VT = has_vt ? VTs : YT;
    u32* MFp = (use_mt && has_flag) ? MF : (u32*)nullptr;

    if (MFp)
        hipMemsetAsync(MFp, 0, 4, stream);
    // single prep launch: transpose (4096 blocks) + weight cvt (512) + mask^T (4096)
    k_prep<<<use_mt ? 8704 : 4608, 256, 0, stream>>>(x, y, Wk, Wv, Wq, Wf, mask,
                                                     XT, YT, WKB, WVB, WQB, WFB, MT, MFp);
    if (has_vt) {
        // single fused launch: Q (reads YT), K, V (writes separate VTs)
        k_proj3<<<768, 256, 0, stream>>>(XT, YT, WKB, WVB, WQB, KT, VT, QT, 0);
    } else {
        // launch 1: Q (reads YT) + K; launch 2: V (writes VT == YT, safe after launch 1)
        k_proj3<<<512, 256, 0, stream>>>(XT, YT, WKB, WVB, WQB, KT, VT, QT, 0);
        k_proj3<<<256, 256, 0, stream>>>(XT, YT, WKB, WVB, WQB, KT, VT, QT, 2);
    }
    if (use_mt)
        k_attn<1><<<512, 512, 0, stream>>>(KT, QT, VT, mask, MT, MFp, OA);
    else
        k_attn<0><<<512, 512, 0, stream>>>(KT, QT, VT, mask, MT, MFp, OA);
    k_final<<<512, 256, 0, stream>>>(OA, WFB, bias, out);
}